// Round 1
// baseline (2158.670 us; speedup 1.0000x reference)
//
#include <hip/hip_runtime.h>
#include <math.h>

#define NN 50000
#define NE 600000
#define D 128

typedef unsigned int u32;

__global__ __launch_bounds__(256) void k_deg(const int* __restrict__ src,
                                             const int* __restrict__ dst,
                                             u32* __restrict__ dout,
                                             u32* __restrict__ din, int E) {
  int e = blockIdx.x * 256 + threadIdx.x;
  if (e >= E) return;
  atomicAdd(&dout[src[e]], 1u);
  atomicAdd(&din[dst[e]], 1u);
}

// norms; also writes the "ones" vector used for layer-2 (ns already folded
// into h1 by the gemm epilogue).
__global__ __launch_bounds__(256) void k_norm(const u32* __restrict__ dout,
                                              const u32* __restrict__ din,
                                              float* __restrict__ ns,
                                              float* __restrict__ nd,
                                              float* __restrict__ ones, int n) {
  int i = blockIdx.x * 256 + threadIdx.x;
  if (i >= n) return;
  float o = (float)dout[i]; o = o < 1.f ? 1.f : o;
  float d = (float)din[i];  d = d < 1.f ? 1.f : d;
  ns[i] = 1.f / sqrtf(o);
  nd[i] = 1.f / sqrtf(d);
  ones[i] = 1.0f;
}

// 32 lanes per edge, float4 per lane. Source-side norm fused into weight.
__global__ __launch_bounds__(256) void k_edge(const float* __restrict__ h,
                                              const float* __restrict__ ns,
                                              const int* __restrict__ src,
                                              const int* __restrict__ dst,
                                              const float* __restrict__ ew,
                                              float* __restrict__ agg, int E) {
  int idx = blockIdx.x * 256 + threadIdx.x;
  int e = idx >> 5;
  if (e >= E) return;
  int o4 = (idx & 31) << 2;
  int s = src[e], d = dst[e];
  float w = ew[e] * ns[s];
  const float4 v = *(const float4*)(h + (size_t)s * D + o4);
  float* b = agg + (size_t)d * D + o4;
  unsafeAtomicAdd(b + 0, v.x * w);
  unsafeAtomicAdd(b + 1, v.y * w);
  unsafeAtomicAdd(b + 2, v.z * w);
  unsafeAtomicAdd(b + 3, v.w * w);
}

// out[i,:] = act(nd[i]*(A[i,:]@W) + b) [* ns[i] if SCALE_OUT]
template <int RELU, int SCALE_OUT>
__global__ __launch_bounds__(256) void k_gemm(const float* __restrict__ A,
                                              const float* __restrict__ nd,
                                              const float* __restrict__ ns,
                                              const float* __restrict__ W,
                                              const float* __restrict__ bias,
                                              float* __restrict__ out, int n) {
  __shared__ float sW[D * D];
  __shared__ float sRow[4][D];
  for (int t = threadIdx.x; t < D * D; t += 256) sW[t] = W[t];
  __syncthreads();
  const int wave = threadIdx.x >> 6, lane = threadIdx.x & 63;
  const float2 bv = *(const float2*)(bias + 2 * lane);
  for (int row = blockIdx.x * 4 + wave; row < n; row += gridDim.x * 4) {
    float2 rv = *(const float2*)(A + (size_t)row * D + 2 * lane);
    sRow[wave][2 * lane] = rv.x;
    sRow[wave][2 * lane + 1] = rv.y;
    float a0 = 0.f, a1 = 0.f;
#pragma unroll
    for (int k = 0; k < D; ++k) {
      float r = sRow[wave][k];
      a0 += r * sW[k * D + 2 * lane];
      a1 += r * sW[k * D + 2 * lane + 1];
    }
    float ndv = nd[row];
    float o0 = a0 * ndv + bv.x;
    float o1 = a1 * ndv + bv.y;
    if (RELU) { o0 = fmaxf(o0, 0.f); o1 = fmaxf(o1, 0.f); }
    if (SCALE_OUT) { float s = ns[row]; o0 *= s; o1 *= s; }
    *(float2*)(out + (size_t)row * D + 2 * lane) = make_float2(o0, o1);
  }
}

extern "C" void kernel_launch(void* const* d_in, const int* in_sizes, int n_in,
                              void* d_out, int out_size, void* d_ws, size_t ws_size,
                              hipStream_t stream) {
  const float* features = (const float*)d_in[0];
  const float* edge_w   = (const float*)d_in[1];
  const float* W1       = (const float*)d_in[2];
  const float* b1       = (const float*)d_in[3];
  const float* W2       = (const float*)d_in[4];
  const float* b2       = (const float*)d_in[5];
  const int*   esrc     = (const int*)d_in[6];
  const int*   edst     = (const int*)d_in[7];
  float* out = (float*)d_out;

  char* ws = (char*)d_ws;
  const size_t nd_bytes = (size_t)NN * D * 4;      // 25.6 MB
  u32*   deg_out = (u32*)(ws);                     // [0, 200000)
  u32*   deg_in  = (u32*)(ws + 200000);            // [200000, 400000)
  float* ns      = (float*)(ws + 400000);
  float* nd      = (float*)(ws + 600000);
  float* ones    = (float*)(ws + 800000);
  float* bufA    = (float*)(ws + 1000000);                  // h1 (ns-prescaled)
  float* bufB    = (float*)(ws + 1000000 + nd_bytes);       // agg

  hipMemsetAsync(deg_out, 0, 2 * 200000, stream);
  k_deg<<<(NE + 255) / 256, 256, 0, stream>>>(esrc, edst, deg_out, deg_in, NE);
  k_norm<<<(NN + 255) / 256, 256, 0, stream>>>(deg_out, deg_in, ns, nd, ones, NN);

  const int egrid = (NE * 32 + 255) / 256;

  // layer 1
  hipMemsetAsync(bufB, 0, nd_bytes, stream);
  k_edge<<<egrid, 256, 0, stream>>>(features, ns, esrc, edst, edge_w, bufB, NE);
  k_gemm<1, 1><<<1024, 256, 0, stream>>>(bufB, nd, ns, W1, b1, bufA, NN);

  // layer 2 (bufA already carries ns; pass ones as source norm)
  hipMemsetAsync(bufB, 0, nd_bytes, stream);
  k_edge<<<egrid, 256, 0, stream>>>(bufA, ones, esrc, edst, edge_w, bufB, NE);
  k_gemm<0, 0><<<1024, 256, 0, stream>>>(bufB, nd, ns, W2, b2, out, NN);
}

// Round 2
// 348.778 us; speedup vs baseline: 6.1892x; 6.1892x over previous
//
#include <hip/hip_runtime.h>
#include <math.h>

#define NN 50000
#define NE 600000
#define D 128

typedef unsigned int u32;

// ---------------- degree histogram ----------------
__global__ __launch_bounds__(256) void k_deg(const int* __restrict__ src,
                                             const int* __restrict__ dst,
                                             u32* __restrict__ dout,
                                             u32* __restrict__ din, int E) {
  int e = blockIdx.x * 256 + threadIdx.x;
  if (e >= E) return;
  atomicAdd(&dout[src[e]], 1u);
  atomicAdd(&din[dst[e]], 1u);
}

// ---------------- norms + CSR segment allocation ----------------
// start[i]/cursor[i] get a contiguous region of size deg_in[i] via a bump
// allocator; region order is irrelevant (segments are disjoint).
__global__ __launch_bounds__(256) void k_norm_alloc(const u32* __restrict__ dout,
                                                    const u32* __restrict__ din,
                                                    float* __restrict__ ns,
                                                    float* __restrict__ nd,
                                                    u32* __restrict__ start,
                                                    u32* __restrict__ cursor,
                                                    u32* __restrict__ total, int n) {
  int i = blockIdx.x * 256 + threadIdx.x;
  if (i >= n) return;
  float o = (float)dout[i]; o = o < 1.f ? 1.f : o;
  float d = (float)din[i];  d = d < 1.f ? 1.f : d;
  ns[i] = 1.f / sqrtf(o);
  nd[i] = 1.f / sqrtf(d);
  u32 st = atomicAdd(total, din[i]);
  start[i] = st;
  cursor[i] = st;
}

// ---------------- pre-scale features by ns (row-wise) ----------------
__global__ __launch_bounds__(256) void k_prescale(const float* __restrict__ in,
                                                  const float* __restrict__ ns,
                                                  float* __restrict__ out, int n4) {
  int i = blockIdx.x * 256 + threadIdx.x;
  if (i >= n4) return;
  int row = i >> 5;                 // 32 float4 per row (D=128)
  float s = ns[row];
  float4 v = ((const float4*)in)[i];
  v.x *= s; v.y *= s; v.z *= s; v.w *= s;
  ((float4*)out)[i] = v;
}

// ---------------- scatter edges into CSR slots ----------------
// sedge[p] = (src, bitcast(weight)); one 8B write per edge.
__global__ __launch_bounds__(256) void k_scatter(const int* __restrict__ src,
                                                 const int* __restrict__ dst,
                                                 const float* __restrict__ ew,
                                                 u32* __restrict__ cursor,
                                                 int2* __restrict__ sedge, int E) {
  int e = blockIdx.x * 256 + threadIdx.x;
  if (e >= E) return;
  int d = dst[e];
  u32 p = atomicAdd(&cursor[d], 1u);
  sedge[p] = make_int2(src[e], __float_as_int(ew[e]));
}

// ---------------- CSR gather-accumulate: one wave per dst node ----------------
__global__ __launch_bounds__(256) void k_gather(const float* __restrict__ h,
                                                const int2* __restrict__ sedge,
                                                const u32* __restrict__ start,
                                                const u32* __restrict__ deg,
                                                float* __restrict__ agg, int n) {
  int node = blockIdx.x * 4 + (threadIdx.x >> 6);
  if (node >= n) return;
  int lane = threadIdx.x & 63;
  u32 s0 = start[node], cnt = deg[node];
  float ax = 0.f, ay = 0.f;
  for (u32 k = 0; k < cnt; ++k) {
    int2 sw = sedge[s0 + k];
    float w = __int_as_float(sw.y);
    const float2 v = *(const float2*)(h + (size_t)sw.x * D + 2 * lane);
    ax += w * v.x;
    ay += w * v.y;
  }
  *(float2*)(agg + (size_t)node * D + 2 * lane) = make_float2(ax, ay);
}

// out[i,:] = act(nd[i]*(A[i,:]@W) + b) [* ns[i] if SCALE_OUT]
template <int RELU, int SCALE_OUT>
__global__ __launch_bounds__(256) void k_gemm(const float* __restrict__ A,
                                              const float* __restrict__ nd,
                                              const float* __restrict__ ns,
                                              const float* __restrict__ W,
                                              const float* __restrict__ bias,
                                              float* __restrict__ out, int n) {
  __shared__ float sW[D * D];
  __shared__ float sRow[4][D];
  for (int t = threadIdx.x; t < D * D; t += 256) sW[t] = W[t];
  __syncthreads();
  const int wave = threadIdx.x >> 6, lane = threadIdx.x & 63;
  const float2 bv = *(const float2*)(bias + 2 * lane);
  for (int row = blockIdx.x * 4 + wave; row < n; row += gridDim.x * 4) {
    float2 rv = *(const float2*)(A + (size_t)row * D + 2 * lane);
    sRow[wave][2 * lane] = rv.x;
    sRow[wave][2 * lane + 1] = rv.y;
    float a0 = 0.f, a1 = 0.f;
#pragma unroll
    for (int k = 0; k < D; ++k) {
      float r = sRow[wave][k];
      a0 += r * sW[k * D + 2 * lane];
      a1 += r * sW[k * D + 2 * lane + 1];
    }
    float ndv = nd[row];
    float o0 = a0 * ndv + bv.x;
    float o1 = a1 * ndv + bv.y;
    if (RELU) { o0 = fmaxf(o0, 0.f); o1 = fmaxf(o1, 0.f); }
    if (SCALE_OUT) { float s = ns[row]; o0 *= s; o1 *= s; }
    *(float2*)(out + (size_t)row * D + 2 * lane) = make_float2(o0, o1);
  }
}

extern "C" void kernel_launch(void* const* d_in, const int* in_sizes, int n_in,
                              void* d_out, int out_size, void* d_ws, size_t ws_size,
                              hipStream_t stream) {
  const float* features = (const float*)d_in[0];
  const float* edge_w   = (const float*)d_in[1];
  const float* W1       = (const float*)d_in[2];
  const float* b1       = (const float*)d_in[3];
  const float* W2       = (const float*)d_in[4];
  const float* b2       = (const float*)d_in[5];
  const int*   esrc     = (const int*)d_in[6];
  const int*   edst     = (const int*)d_in[7];
  float* out = (float*)d_out;

  char* ws = (char*)d_ws;
  const size_t nd_bytes = (size_t)NN * D * 4;              // 25.6 MB
  u32*   deg_out = (u32*)(ws);                             // 200 KB
  u32*   deg_in  = (u32*)(ws + 200000);
  float* ns      = (float*)(ws + 400000);
  float* nd      = (float*)(ws + 600000);
  u32*   start   = (u32*)(ws + 800000);
  u32*   cursor  = (u32*)(ws + 1000000);
  u32*   total   = (u32*)(ws + 1200000);                   // 4 B
  int2*  sedge   = (int2*)(ws + 1200640);                  // 4.8 MB
  float* bufA    = (float*)(ws + 6001664);                 // 25.6 MB
  float* bufB    = (float*)(ws + 6001664 + nd_bytes);      // 25.6 MB

  // degrees, norms, CSR allocation
  hipMemsetAsync(deg_out, 0, 2 * 200000, stream);          // deg_out + deg_in
  hipMemsetAsync(total, 0, 4, stream);
  k_deg<<<(NE + 255) / 256, 256, 0, stream>>>(esrc, edst, deg_out, deg_in, NE);
  k_norm_alloc<<<(NN + 255) / 256, 256, 0, stream>>>(deg_out, deg_in, ns, nd,
                                                     start, cursor, total, NN);
  k_scatter<<<(NE + 255) / 256, 256, 0, stream>>>(esrc, edst, edge_w, cursor,
                                                  sedge, NE);

  // layer 1: bufA = ns*features (prescale), gather -> bufB, gemm -> bufA
  k_prescale<<<(NN * D / 4 + 255) / 256, 256, 0, stream>>>(features, ns, bufA,
                                                           NN * D / 4);
  k_gather<<<(NN + 3) / 4, 256, 0, stream>>>(bufA, sedge, start, deg_in, bufB, NN);
  k_gemm<1, 1><<<1024, 256, 0, stream>>>(bufB, nd, ns, W1, b1, bufA, NN);

  // layer 2: bufA already ns-prescaled by gemm1 epilogue
  k_gather<<<(NN + 3) / 4, 256, 0, stream>>>(bufA, sedge, start, deg_in, bufB, NN);
  k_gemm<0, 0><<<1024, 256, 0, stream>>>(bufB, nd, ns, W2, b2, out, NN);
}

// Round 3
// 273.941 us; speedup vs baseline: 7.8801x; 1.2732x over previous
//
#include <hip/hip_runtime.h>
#include <math.h>

#define NN 50000
#define NE 600000
#define D 128

typedef unsigned int u32;

// ---------------- degree histogram ----------------
__global__ __launch_bounds__(256) void k_deg(const int* __restrict__ src,
                                             const int* __restrict__ dst,
                                             u32* __restrict__ dout,
                                             u32* __restrict__ din, int E) {
  int e = blockIdx.x * 256 + threadIdx.x;
  if (e >= E) return;
  atomicAdd(&dout[src[e]], 1u);
  atomicAdd(&din[dst[e]], 1u);
}

// ---------------- norms + CSR segment allocation (bump allocator) ----------------
__global__ __launch_bounds__(256) void k_norm_alloc(const u32* __restrict__ dout,
                                                    const u32* __restrict__ din,
                                                    float* __restrict__ ns,
                                                    float* __restrict__ nd,
                                                    u32* __restrict__ start,
                                                    u32* __restrict__ cursor,
                                                    u32* __restrict__ total, int n) {
  int i = blockIdx.x * 256 + threadIdx.x;
  if (i >= n) return;
  float o = (float)dout[i]; o = o < 1.f ? 1.f : o;
  float d = (float)din[i];  d = d < 1.f ? 1.f : d;
  ns[i] = 1.f / sqrtf(o);
  nd[i] = 1.f / sqrtf(d);
  u32 st = atomicAdd(total, din[i]);
  start[i] = st;
  cursor[i] = st;
}

// ---------------- scatter edges into CSR slots, ns[src] folded into weight ----
// w = ew[e]*ns[src] is correct for BOTH layers (layer inputs kept unscaled).
__global__ __launch_bounds__(256) void k_scatter(const int* __restrict__ src,
                                                 const int* __restrict__ dst,
                                                 const float* __restrict__ ew,
                                                 const float* __restrict__ ns,
                                                 u32* __restrict__ cursor,
                                                 int2* __restrict__ sedge, int E) {
  int e = blockIdx.x * 256 + threadIdx.x;
  if (e >= E) return;
  int d = dst[e], s = src[e];
  u32 p = atomicAdd(&cursor[d], 1u);
  sedge[p] = make_int2(s, __float_as_int(ew[e] * ns[s]));
}

// ---------------- CSR gather-accumulate: one wave per dst node, unroll x4 ----
__global__ __launch_bounds__(256) void k_gather(const float* __restrict__ h,
                                                const int2* __restrict__ sedge,
                                                const u32* __restrict__ start,
                                                const u32* __restrict__ deg,
                                                float* __restrict__ agg, int n) {
  int node = blockIdx.x * 4 + (threadIdx.x >> 6);
  if (node >= n) return;
  int lane = threadIdx.x & 63;
  const size_t off = 2 * (size_t)lane;
  u32 s0 = start[node], cnt = deg[node];
  float ax = 0.f, ay = 0.f;
  u32 k = 0;
  for (; k + 4 <= cnt; k += 4) {
    int2 e0 = sedge[s0 + k + 0];
    int2 e1 = sedge[s0 + k + 1];
    int2 e2 = sedge[s0 + k + 2];
    int2 e3 = sedge[s0 + k + 3];
    float2 v0 = *(const float2*)(h + (size_t)e0.x * D + off);
    float2 v1 = *(const float2*)(h + (size_t)e1.x * D + off);
    float2 v2 = *(const float2*)(h + (size_t)e2.x * D + off);
    float2 v3 = *(const float2*)(h + (size_t)e3.x * D + off);
    float w0 = __int_as_float(e0.y), w1 = __int_as_float(e1.y);
    float w2 = __int_as_float(e2.y), w3 = __int_as_float(e3.y);
    ax += w0 * v0.x; ay += w0 * v0.y;
    ax += w1 * v1.x; ay += w1 * v1.y;
    ax += w2 * v2.x; ay += w2 * v2.y;
    ax += w3 * v3.x; ay += w3 * v3.y;
  }
  for (; k < cnt; ++k) {
    int2 e = sedge[s0 + k];
    float w = __int_as_float(e.y);
    float2 v = *(const float2*)(h + (size_t)e.x * D + off);
    ax += w * v.x; ay += w * v.y;
  }
  *(float2*)(agg + (size_t)node * D + off) = make_float2(ax, ay);
}

// ---------------- node GEMM: 4 rows/wave, W + transposed rows in LDS --------
// out[i,:] = act(nd[i]*(A[i,:]@W) + b);  50000 % 16 == 0, no tail.
template <int RELU>
__global__ __launch_bounds__(256) void k_gemm(const float* __restrict__ A,
                                              const float* __restrict__ nd,
                                              const float* __restrict__ W,
                                              const float* __restrict__ bias,
                                              float* __restrict__ out, int n) {
  __shared__ float sW[D * D];          // 64 KB
  __shared__ float sRowA[4][D][4];     // 8 KB, per-wave private slab
  for (int t = threadIdx.x; t < D * D; t += 256) sW[t] = W[t];
  const int wave = threadIdx.x >> 6, lane = threadIdx.x & 63;
  const float2 bv = *(const float2*)(bias + 2 * lane);
  __syncthreads();
  for (int base = blockIdx.x * 16; base < n; base += gridDim.x * 16) {
    const int row0 = base + wave * 4;
    // stage 4 rows, transposed so one b128 broadcast yields 4 row-values
#pragma unroll
    for (int r = 0; r < 4; ++r) {
      float2 rv = *(const float2*)(A + (size_t)(row0 + r) * D + 2 * lane);
      sRowA[wave][2 * lane][r] = rv.x;
      sRowA[wave][2 * lane + 1][r] = rv.y;
    }
    __syncthreads();   // uniform; also orders same-wave LDS write->read
    float a00 = 0.f, a01 = 0.f, a10 = 0.f, a11 = 0.f;
    float a20 = 0.f, a21 = 0.f, a30 = 0.f, a31 = 0.f;
#pragma unroll 4
    for (int k = 0; k < D; ++k) {
      float2 w = *(const float2*)(&sW[k * D + 2 * lane]);
      float4 rr = *(const float4*)(&sRowA[wave][k][0]);
      a00 += rr.x * w.x; a01 += rr.x * w.y;
      a10 += rr.y * w.x; a11 += rr.y * w.y;
      a20 += rr.z * w.x; a21 += rr.z * w.y;
      a30 += rr.w * w.x; a31 += rr.w * w.y;
    }
    float n0 = nd[row0], n1 = nd[row0 + 1], n2 = nd[row0 + 2], n3 = nd[row0 + 3];
    float o00 = a00 * n0 + bv.x, o01 = a01 * n0 + bv.y;
    float o10 = a10 * n1 + bv.x, o11 = a11 * n1 + bv.y;
    float o20 = a20 * n2 + bv.x, o21 = a21 * n2 + bv.y;
    float o30 = a30 * n3 + bv.x, o31 = a31 * n3 + bv.y;
    if (RELU) {
      o00 = fmaxf(o00, 0.f); o01 = fmaxf(o01, 0.f);
      o10 = fmaxf(o10, 0.f); o11 = fmaxf(o11, 0.f);
      o20 = fmaxf(o20, 0.f); o21 = fmaxf(o21, 0.f);
      o30 = fmaxf(o30, 0.f); o31 = fmaxf(o31, 0.f);
    }
    *(float2*)(out + (size_t)(row0 + 0) * D + 2 * lane) = make_float2(o00, o01);
    *(float2*)(out + (size_t)(row0 + 1) * D + 2 * lane) = make_float2(o10, o11);
    *(float2*)(out + (size_t)(row0 + 2) * D + 2 * lane) = make_float2(o20, o21);
    *(float2*)(out + (size_t)(row0 + 3) * D + 2 * lane) = make_float2(o30, o31);
    __syncthreads();   // protect sRowA before next iteration's staging
  }
}

extern "C" void kernel_launch(void* const* d_in, const int* in_sizes, int n_in,
                              void* d_out, int out_size, void* d_ws, size_t ws_size,
                              hipStream_t stream) {
  const float* features = (const float*)d_in[0];
  const float* edge_w   = (const float*)d_in[1];
  const float* W1       = (const float*)d_in[2];
  const float* b1       = (const float*)d_in[3];
  const float* W2       = (const float*)d_in[4];
  const float* b2       = (const float*)d_in[5];
  const int*   esrc     = (const int*)d_in[6];
  const int*   edst     = (const int*)d_in[7];
  float* out = (float*)d_out;

  char* ws = (char*)d_ws;
  const size_t nd_bytes = (size_t)NN * D * 4;              // 25.6 MB
  u32*   deg_out = (u32*)(ws);
  u32*   deg_in  = (u32*)(ws + 200000);
  float* ns      = (float*)(ws + 400000);
  float* nd      = (float*)(ws + 600000);
  u32*   start   = (u32*)(ws + 800000);
  u32*   cursor  = (u32*)(ws + 1000000);
  u32*   total   = (u32*)(ws + 1200000);
  int2*  sedge   = (int2*)(ws + 1200640);                  // 4.8 MB
  float* bufA    = (float*)(ws + 6001664);                 // h1
  float* bufB    = (float*)(ws + 6001664 + nd_bytes);      // agg

  // degrees, norms, CSR
  hipMemsetAsync(deg_out, 0, 2 * 200000, stream);
  hipMemsetAsync(total, 0, 4, stream);
  k_deg<<<(NE + 255) / 256, 256, 0, stream>>>(esrc, edst, deg_out, deg_in, NE);
  k_norm_alloc<<<(NN + 255) / 256, 256, 0, stream>>>(deg_out, deg_in, ns, nd,
                                                     start, cursor, total, NN);
  k_scatter<<<(NE + 255) / 256, 256, 0, stream>>>(esrc, edst, edge_w, ns, cursor,
                                                  sedge, NE);

  // layer 1
  k_gather<<<(NN + 3) / 4, 256, 0, stream>>>(features, sedge, start, deg_in, bufB, NN);
  k_gemm<1><<<512, 256, 0, stream>>>(bufB, nd, W1, b1, bufA, NN);

  // layer 2
  k_gather<<<(NN + 3) / 4, 256, 0, stream>>>(bufA, sedge, start, deg_in, bufB, NN);
  k_gemm<0><<<512, 256, 0, stream>>>(bufB, nd, W2, b2, out, NN);
}